// Round 1
// baseline (574.254 us; speedup 1.0000x reference)
//
#include <hip/hip_runtime.h>
#include <stdint.h>
#include <stddef.h>

// HardNegativeMiningLoss on MI355X.
// Pipeline: kinit -> kconv(bf16) -> khist -> kpos(positive stats via ballot scan)
//        -> kgemm(bf16 MFMA sim tiles + in-register top-16 mining, per col-block partials)
//        -> kfin(merge partials, masked LSE, reduce) -> kout(divide).
//
// B=8192, D=512, K=16, TEMP=0.07, labels in [0,2048).

#define TEMPV 0.07f
#define NEGV -1e30f

typedef short v8s __attribute__((ext_vector_type(8)));
typedef float v4f __attribute__((ext_vector_type(4)));

__device__ __forceinline__ short f2bf(float f) {
  unsigned u = __float_as_uint(f);
  unsigned r = (u + 0x7fffu + ((u >> 16) & 1u)) >> 16;  // RNE
  return (short)r;
}
__device__ __forceinline__ float bf2f(short s) {
  return __uint_as_float(((unsigned)(unsigned short)s) << 16);
}

__device__ __forceinline__ void gload16(const void* g, void* l) {
  // async global->LDS, 16B/lane; LDS dest is wave-uniform base + lane*16 (linear)
  __builtin_amdgcn_global_load_lds((const __attribute__((address_space(1))) unsigned*)g,
                                   (__attribute__((address_space(3))) unsigned*)l, 16, 0, 0);
}

// Sorted-ascending top-16 list; call only when v > L[0]. Branchless shift, static idx.
__device__ __forceinline__ void ins16(float (&L)[16], float v) {
#pragma unroll
  for (int k = 0; k < 15; ++k) {
    float lo = fminf(v, L[k + 1]);
    float hi = fmaxf(v, L[k + 1]);
    L[k] = lo;
    v = hi;
  }
  L[15] = v;
}

__global__ void kinit(int* hist, float* lsum, int* nval) {
  int i = blockIdx.x * blockDim.x + threadIdx.x;
  if (i < 2048) hist[i] = 0;
  if (i == 0) { *lsum = 0.f; *nval = 0; }
}

__global__ void kconv(const float* __restrict__ emb, short* __restrict__ emb16) {
  int i = (blockIdx.x * 256 + threadIdx.x) * 4;
  float4 v = *(const float4*)(emb + i);
  short4 s;
  s.x = f2bf(v.x); s.y = f2bf(v.y); s.z = f2bf(v.z); s.w = f2bf(v.w);
  *(short4*)(emb16 + i) = s;
}

__global__ void khist(const int* __restrict__ lab, int* hist) {
  int i = blockIdx.x * 256 + threadIdx.x;
  if (i < 8192) atomicAdd(&hist[lab[i]], 1);
}

// One wave per row: find same-label rows via ballot over LDS labels, fp32 dot for each
// positive (uses the SAME bf16-rounded embeddings as the GEMM for consistency).
__global__ __launch_bounds__(256) void kpos(const short* __restrict__ emb16,
                                            const int* __restrict__ lab,
                                            const int* __restrict__ hist,
                                            float* __restrict__ pmin,
                                            float* __restrict__ pterm,
                                            int* __restrict__ valid) {
  __shared__ int labs[8192];
  int t = threadIdx.x;
  for (int j = t; j < 8192; j += 256) labs[j] = lab[j];
  __syncthreads();
  int w = t >> 6, lane = t & 63;
  int i = blockIdx.x * 4 + w;
  int li = labs[i];
  float ei[8];
  v8s e = *(const v8s*)(emb16 + (size_t)i * 512 + lane * 8);
#pragma unroll
  for (int k = 0; k < 8; ++k) ei[k] = bf2f(e[k]);
  float smin = 1e30f, ssum = 0.f;
  for (int j0 = 0; j0 < 8192; j0 += 64) {
    int j = j0 + lane;
    bool p = (labs[j] == li) && (j != i);
    unsigned long long m = __ballot(p);
    while (m) {
      int b = __builtin_ctzll(m);
      m &= m - 1;
      int jj = j0 + b;
      v8s f = *(const v8s*)(emb16 + (size_t)jj * 512 + lane * 8);
      float s = 0.f;
#pragma unroll
      for (int k = 0; k < 8; ++k) s += ei[k] * bf2f(f[k]);
#pragma unroll
      for (int off = 32; off; off >>= 1) s += __shfl_xor(s, off);
      smin = fminf(smin, s);
      ssum += s;
    }
  }
  if (lane == 0) {
    int h = hist[li];
    int pc = h - 1, nc = 8192 - h;
    pmin[i] = smin;  // +1e30 when no positives, matching ref's where-fill
    pterm[i] = ssum / (float)(pc > 0 ? pc : 1) / TEMPV;
    valid[i] = (pc > 0 && nc > 0) ? 1 : 0;
  }
}

// Main mining GEMM. Grid: 512 = 64 row-blocks(BM=128) x 8 col-blocks(1024 cols, bid&7 -> XCD).
// 4 waves as 2x2; wave tile = 64 rows x 32 cols; MFMA operands swapped so D's col(lane&15)
// dim is the sim-ROW -> epilogue writes per-row-contiguous float4s into padded LDS, then
// 2 scan threads per row maintain top-16(all-neg) + top-16(semi) sorted lists in registers.
__global__ __launch_bounds__(256, 2) void kgemm(const short* __restrict__ emb16,
                                                const int* __restrict__ lab,
                                                const float* __restrict__ pminA,
                                                float* __restrict__ Lall,
                                                float* __restrict__ Lsemi,
                                                int* __restrict__ Scnt) {
  __shared__ short Rs[8][128][8];   // row-block K-tile, chunk-major (16KB)
  __shared__ short Cg[8][64][8];    // col-tile K-tile (8KB)
  __shared__ float Cbuf[128][68];   // sim tile scan buffer, padded stride 68 (34KB)
  __shared__ int scntS[128];

  int t = threadIdx.x;
  int bid = blockIdx.x;
  int rb = bid >> 3, cb = bid & 7;
  int rowbase = rb * 128;
  int colblock = cb * 1024;

  int w = t >> 6, l = t & 63;
  int wr = w >> 1, wc = w & 1;
  int l15 = l & 15, l4 = l >> 4;

  int srow = t & 127, shalf = t >> 7;
  int rlab = lab[rowbase + srow];
  float pm = pminA[rowbase + srow];
  float la[16], ls[16];
#pragma unroll
  for (int k = 0; k < 16; ++k) { la[k] = NEGV; ls[k] = NEGV; }
  int sc = 0;

  for (int tile = 0; tile < 16; ++tile) {
    int colstart = colblock + tile * 64;
    v4f acc[2][4];
#pragma unroll
    for (int mi = 0; mi < 2; ++mi)
#pragma unroll
      for (int fi = 0; fi < 4; ++fi) acc[mi][fi] = (v4f)0.f;

    for (int ks = 0; ks < 8; ++ks) {
      int kbase = ks * 64;
      // stage R (128x64 bf16 = 16KB = 4 calls) and C (64x64 = 8KB = 2 calls)
#pragma unroll
      for (int q = 0; q < 4; ++q) {
        int e = q * 256 + t;
        int ch = e >> 7, idx = e & 127;
        gload16(emb16 + ((size_t)(rowbase + idx) * 512 + kbase + ch * 8),
                &Rs[ch][idx][0]);
      }
#pragma unroll
      for (int q = 0; q < 2; ++q) {
        int e = q * 256 + t;
        int ch = e >> 6, idx = e & 63;
        gload16(emb16 + ((size_t)(colstart + idx) * 512 + kbase + ch * 8),
                &Cg[ch][idx][0]);
      }
      __syncthreads();  // compiler emits vmcnt(0) drain before s_barrier
#pragma unroll
      for (int h = 0; h < 2; ++h) {
        v8s a[2], b[4];
#pragma unroll
        for (int mi = 0; mi < 2; ++mi)
          a[mi] = *(const v8s*)&Cg[h * 4 + l4][wc * 32 + mi * 16 + l15][0];
#pragma unroll
        for (int fi = 0; fi < 4; ++fi)
          b[fi] = *(const v8s*)&Rs[h * 4 + l4][wr * 64 + fi * 16 + l15][0];
#pragma unroll
        for (int mi = 0; mi < 2; ++mi)
#pragma unroll
          for (int fi = 0; fi < 4; ++fi)
            acc[mi][fi] = __builtin_amdgcn_mfma_f32_16x16x32_bf16(a[mi], b[fi],
                                                                  acc[mi][fi], 0, 0, 0);
      }
      __syncthreads();
    }

    // epilogue: D row=(l>>4)*4+reg is the sim-COL (a-operand), col=l&15 is the sim-ROW
#pragma unroll
    for (int mi = 0; mi < 2; ++mi)
#pragma unroll
      for (int fi = 0; fi < 4; ++fi) {
        int row = wr * 64 + fi * 16 + l15;
        int col = wc * 32 + mi * 16 + l4 * 4;
        *(float4*)&Cbuf[row][col] = *(float4*)&acc[mi][fi];
      }
    __syncthreads();
    // scan: 2 threads per row, 32 cols each; col labels are wave-uniform -> scalar loads
#pragma unroll 4
    for (int k = 0; k < 32; ++k) {
      int col = shalf * 32 + k;
      float v = Cbuf[srow][col];
      int cl = lab[colstart + col];
      if (cl != rlab) {
        if (v > la[0]) ins16(la, v);
        if (v < pm) {
          sc++;
          if (v > ls[0]) ins16(ls, v);
        }
      }
    }
    // no barrier needed: next Cbuf write is separated by >=8 ks-loop barriers
  }

  // merge the two half-scanners of each row, write per-col-block partials
  __syncthreads();
  if (shalf == 1) {
#pragma unroll
    for (int k = 0; k < 16; ++k) {
      Cbuf[srow][k] = la[k];
      Cbuf[srow][16 + k] = ls[k];
    }
    scntS[srow] = sc;
  }
  __syncthreads();
  if (shalf == 0) {
#pragma unroll
    for (int k = 0; k < 16; ++k) {
      float v = Cbuf[srow][k];
      if (v > la[0]) ins16(la, v);
    }
#pragma unroll
    for (int k = 0; k < 16; ++k) {
      float v = Cbuf[srow][16 + k];
      if (v > ls[0]) ins16(ls, v);
    }
    sc += scntS[srow];
    size_t o = ((size_t)cb * 8192 + rowbase + srow) * 16;
#pragma unroll
    for (int k = 0; k < 16; ++k) { Lall[o + k] = la[k]; Lsemi[o + k] = ls[k]; }
    Scnt[cb * 8192 + rowbase + srow] = sc;
  }
}

// Merge 8 col-block partials per row, masked LSE (sentinel -1e30 == ref kmask), reduce.
__global__ __launch_bounds__(256) void kfin(const float* __restrict__ Lall,
                                            const float* __restrict__ Lsemi,
                                            const int* __restrict__ Scnt,
                                            const float* __restrict__ pterm,
                                            const int* __restrict__ valid,
                                            float* lsum, int* nval) {
  int i = blockIdx.x * 256 + threadIdx.x;
  float la[16], ls[16];
#pragma unroll
  for (int k = 0; k < 16; ++k) {
    la[k] = Lall[(size_t)i * 16 + k];
    ls[k] = Lsemi[(size_t)i * 16 + k];
  }
  int sc = Scnt[i];
#pragma unroll
  for (int c = 1; c < 8; ++c) {
    size_t o = ((size_t)c * 8192 + i) * 16;
#pragma unroll
    for (int k = 0; k < 16; ++k) { float v = Lall[o + k]; if (v > la[0]) ins16(la, v); }
#pragma unroll
    for (int k = 0; k < 16; ++k) { float v = Lsemi[o + k]; if (v > ls[0]) ins16(ls, v); }
    sc += Scnt[c * 8192 + i];
  }
  bool hs = sc > 0;
  float sel[16];
#pragma unroll
  for (int k = 0; k < 16; ++k) sel[k] = hs ? ls[k] : la[k];
  float mx = NEGV;
#pragma unroll
  for (int k = 0; k < 16; ++k) {
    float sv = (sel[k] > -1e29f) ? sel[k] / TEMPV : NEGV;
    mx = fmaxf(mx, sv);
  }
  float se = 0.f;
#pragma unroll
  for (int k = 0; k < 16; ++k)
    if (sel[k] > -1e29f) se += expf(sel[k] / TEMPV - mx);
  float lse = mx + logf(fmaxf(se, 1e-30f));
  int vd = valid[i];
  float li = vd ? (lse - pterm[i]) : 0.f;
#pragma unroll
  for (int off = 32; off; off >>= 1) {
    li += __shfl_xor(li, off);
    vd += __shfl_xor(vd, off);
  }
  __shared__ float rsd[4];
  __shared__ int rid[4];
  int wv = threadIdx.x >> 6;
  if ((threadIdx.x & 63) == 0) { rsd[wv] = li; rid[wv] = vd; }
  __syncthreads();
  if (threadIdx.x == 0) {
    atomicAdd(lsum, rsd[0] + rsd[1] + rsd[2] + rsd[3]);
    atomicAdd(nval, rid[0] + rid[1] + rid[2] + rid[3]);
  }
}

__global__ void kout(const float* lsum, const int* nval, float* out) {
  if (threadIdx.x == 0 && blockIdx.x == 0)
    out[0] = lsum[0] / (float)(nval[0] > 0 ? nval[0] : 1);
}

extern "C" void kernel_launch(void* const* d_in, const int* in_sizes, int n_in,
                              void* d_out, int out_size, void* d_ws, size_t ws_size,
                              hipStream_t stream) {
  const float* emb = (const float*)d_in[0];
  const int* lab = (const int*)d_in[1];
  float* out = (float*)d_out;

  char* wsb = (char*)d_ws;
  short* emb16 = (short*)wsb;                      // 8,388,608
  int* hist = (int*)(wsb + 8388608);               // 8,192
  float* pmin = (float*)(wsb + 8396800);           // 32,768
  float* pterm = (float*)(wsb + 8429568);          // 32,768
  int* valid = (int*)(wsb + 8462336);              // 32,768
  float* LallW = (float*)(wsb + 8495104);          // 4,194,304
  float* LsemiW = (float*)(wsb + 12689408);        // 4,194,304
  int* ScntW = (int*)(wsb + 16883712);             // 262,144
  float* lsum = (float*)(wsb + 17145856);          // 4
  int* nval = (int*)(wsb + 17145860);              // 4

  kinit<<<8, 256, 0, stream>>>(hist, lsum, nval);
  kconv<<<4096, 256, 0, stream>>>(emb, emb16);
  khist<<<32, 256, 0, stream>>>(lab, hist);
  kpos<<<2048, 256, 0, stream>>>(emb16, lab, hist, pmin, pterm, valid);
  kgemm<<<512, 256, 0, stream>>>(emb16, lab, pmin, LallW, LsemiW, ScntW);
  kfin<<<32, 256, 0, stream>>>(LallW, LsemiW, ScntW, pterm, valid, lsum, nval);
  kout<<<1, 64, 0, stream>>>(lsum, nval, out);
}

// Round 2
// 275.505 us; speedup vs baseline: 2.0844x; 2.0844x over previous
//
#include <hip/hip_runtime.h>
#include <stdint.h>
#include <stddef.h>

// HardNegativeMiningLoss on MI355X (B=8192, D=512, K=16, TEMP=0.07, labels<2048).
// kinit -> kconv(bf16) -> khist -> kprefix -> kscatter -> kpos2 (positive stats via
// label-index lists) -> kgemm (bf16 MFMA sim tiles + branchless sorting-network
// top-16 mining from accumulators) -> kfin (merge 8 partials, masked LSE) -> kout.

#define TEMPV 0.07f
#define NEGV -1e30f

typedef short v8s __attribute__((ext_vector_type(8)));
typedef float v4f __attribute__((ext_vector_type(4)));

__device__ __forceinline__ short f2bf(float f) {
  unsigned u = __float_as_uint(f);
  unsigned r = (u + 0x7fffu + ((u >> 16) & 1u)) >> 16;  // RNE
  return (short)r;
}
__device__ __forceinline__ float bf2f(short s) {
  return __uint_as_float(((unsigned)(unsigned short)s) << 16);
}

__device__ __forceinline__ void gload16(const void* g, void* l) {
  __builtin_amdgcn_global_load_lds((const __attribute__((address_space(1))) unsigned*)g,
                                   (__attribute__((address_space(3))) unsigned*)l, 16, 0, 0);
}

// ---- Batcher odd-even mergesort network for 16 elements (63 comparators) ----
struct SNet { unsigned char a[64]; unsigned char b[64]; int n; };
constexpr SNet mknet16() {
  SNet t{}; t.n = 0;
  for (int p = 1; p < 16; p <<= 1)
    for (int k = p; k >= 1; k >>= 1)
      for (int j = k % p; j + k < 16; j += 2 * k)
        for (int i = 0; i < k; ++i) {
          int x = i + j, y = i + j + k;
          if (y < 16 && (x / (2 * p)) == (y / (2 * p))) {
            t.a[t.n] = (unsigned char)x; t.b[t.n] = (unsigned char)y; ++t.n;
          }
        }
  return t;
}
constexpr SNet NET16 = mknet16();
constexpr int NETN = NET16.n;

// sort descending (V[0] = max), all indices static after unroll
__device__ __forceinline__ void sort16d(float (&V)[16]) {
#pragma unroll
  for (int c = 0; c < NETN; ++c) {
    const int x = NET16.a[c], y = NET16.b[c];
    float hi = fmaxf(V[x], V[y]);
    float lo = fminf(V[x], V[y]);
    V[x] = hi; V[y] = lo;
  }
}

// clean a bitonic 16-seq into descending order (stages 8,4,2,1)
__device__ __forceinline__ void clean16d(float (&V)[16]) {
#pragma unroll
  for (int s = 8; s >= 1; s >>= 1) {
#pragma unroll
    for (int i = 0; i < 16; ++i) {
      if ((i & s) == 0) {
        float hi = fmaxf(V[i], V[i + s]);
        float lo = fminf(V[i], V[i + s]);
        V[i] = hi; V[i + s] = lo;
      }
    }
  }
}

// merge my desc-16 with xor-partner lane's desc-16 -> both get top-16 of union
__device__ __forceinline__ void xmerge16(float (&M)[16], int mask) {
  float t[16];
#pragma unroll
  for (int i = 0; i < 16; ++i) t[i] = __shfl_xor(M[15 - i], mask);
#pragma unroll
  for (int i = 0; i < 16; ++i) M[i] = fmaxf(M[i], t[i]);
  clean16d(M);
}

// R = top16(R ∪ M), both desc sorted
__device__ __forceinline__ void mergeld(float (&R)[16], const float (&M)[16]) {
  float t[16];
#pragma unroll
  for (int i = 0; i < 16; ++i) t[i] = fmaxf(M[i], R[15 - i]);
#pragma unroll
  for (int i = 0; i < 16; ++i) R[i] = t[i];
  clean16d(R);
}

// ---------------- small setup kernels ----------------
__global__ void kinit(int* hist, int* cur, float* lsum, int* nval) {
  int i = blockIdx.x * blockDim.x + threadIdx.x;
  if (i < 2048) { hist[i] = 0; cur[i] = 0; }
  if (i == 0) { *lsum = 0.f; *nval = 0; }
}

__global__ void kconv(const float* __restrict__ emb, short* __restrict__ emb16) {
  int i = (blockIdx.x * 256 + threadIdx.x) * 4;
  float4 v = *(const float4*)(emb + i);
  short4 s;
  s.x = f2bf(v.x); s.y = f2bf(v.y); s.z = f2bf(v.z); s.w = f2bf(v.w);
  *(short4*)(emb16 + i) = s;
}

__global__ void khist(const int* __restrict__ lab, int* hist) {
  int i = blockIdx.x * 256 + threadIdx.x;
  if (i < 8192) atomicAdd(&hist[lab[i]], 1);
}

__global__ __launch_bounds__(256) void kprefix(const int* __restrict__ hist,
                                               int* __restrict__ start) {
  __shared__ int part[256];
  int t = threadIdx.x;
  int v[8], loc[8], s = 0;
#pragma unroll
  for (int k = 0; k < 8; ++k) v[k] = hist[t * 8 + k];
#pragma unroll
  for (int k = 0; k < 8; ++k) { loc[k] = s; s += v[k]; }
  part[t] = s;
  __syncthreads();
  for (int off = 1; off < 256; off <<= 1) {
    int x = (t >= off) ? part[t - off] : 0;
    __syncthreads();
    part[t] += x;
    __syncthreads();
  }
  int base = (t > 0) ? part[t - 1] : 0;
#pragma unroll
  for (int k = 0; k < 8; ++k) start[t * 8 + k] = base + loc[k];
}

__global__ void kscatter(const int* __restrict__ lab, const int* __restrict__ start,
                         int* cur, int* __restrict__ rows) {
  int i = blockIdx.x * 256 + threadIdx.x;
  if (i < 8192) {
    int li = lab[i];
    int p = atomicAdd(&cur[li], 1);
    rows[start[li] + p] = i;
  }
}

// one wave per row: walk the row's label bucket (~4 entries), fp32 dot per positive
__global__ __launch_bounds__(256) void kpos2(const short* __restrict__ emb16,
                                             const int* __restrict__ lab,
                                             const int* __restrict__ hist,
                                             const int* __restrict__ start,
                                             const int* __restrict__ rows,
                                             float* __restrict__ pmin,
                                             float* __restrict__ pterm,
                                             int* __restrict__ valid) {
  int t = threadIdx.x;
  int wv = t >> 6, lane = t & 63;
  int i = blockIdx.x * 4 + wv;
  int li = lab[i];
  int s0 = start[li], c = hist[li];
  float ei[8];
  v8s e = *(const v8s*)(emb16 + (size_t)i * 512 + lane * 8);
#pragma unroll
  for (int k = 0; k < 8; ++k) ei[k] = bf2f(e[k]);
  float smin = 1e30f, ssum = 0.f;
  for (int k = 0; k < c; ++k) {
    int j = rows[s0 + k];
    if (j == i) continue;
    v8s f = *(const v8s*)(emb16 + (size_t)j * 512 + lane * 8);
    float s = 0.f;
#pragma unroll
    for (int q = 0; q < 8; ++q) s += ei[q] * bf2f(f[q]);
#pragma unroll
    for (int off = 32; off; off >>= 1) s += __shfl_xor(s, off);
    smin = fminf(smin, s);
    ssum += s;
  }
  if (lane == 0) {
    int pc = c - 1, nc = 8192 - c;
    pmin[i] = smin;                                   // +1e30 when no positives
    pterm[i] = ssum / (float)(pc > 0 ? pc : 1) / TEMPV;
    valid[i] = (pc > 0 && nc > 0) ? 1 : 0;
  }
}

// ---------------- main mining GEMM ----------------
// Grid 512 = 64 row-blocks(BM=128) x 8 col-blocks(1024 cols; cb = bid&7 -> XCD).
// 4 waves stacked on rows (32 rows each), BN=128 per tile, BK=64, 8 tiles/block.
// MFMA operands swapped (a=cols, b=rows) so lane's acc values: row = wv*32+fi*16+(l&15),
// col = mi*16 + (l>>4)*4 + r. Mining: per 16-value fragment group -> mask -> Batcher
// sort -> 2x shfl_xor bitonic merge across l4 -> merge into per-row LDS running lists.
__global__ __launch_bounds__(256, 2) void kgemm(const short* __restrict__ emb16,
                                                const int* __restrict__ lab,
                                                const float* __restrict__ pminA,
                                                float* __restrict__ Lall,
                                                float* __restrict__ Lsemi,
                                                int* __restrict__ Scnt) {
  __shared__ short Rs[8][128][8];     // row K-tile, chunk-major (16KB)
  __shared__ short Cg[8][128][8];     // col K-tile (16KB)
  __shared__ float LrA[128][20];      // running top-16 all-neg, stride 20 (conflict-free)
  __shared__ float LrS[128][20];      // running top-16 semi
  __shared__ int scS[128];

  int t = threadIdx.x;
  int bid = blockIdx.x;
  int rb = bid >> 3, cb = bid & 7;
  int rowbase = rb * 128;
  int colblock = cb * 1024;

  int wv = t >> 6, l = t & 63;
  int l15 = l & 15, l4 = l >> 4;

  if (t < 128) {
#pragma unroll
    for (int k = 0; k < 16; ++k) { LrA[t][k] = NEGV; LrS[t][k] = NEGV; }
  }

  int rlabf[2]; float pmf[2]; int scf[2] = {0, 0};
#pragma unroll
  for (int fi = 0; fi < 2; ++fi) {
    int row = rowbase + wv * 32 + fi * 16 + l15;
    rlabf[fi] = lab[row];
    pmf[fi] = pminA[row];
  }
  __syncthreads();

  for (int tile = 0; tile < 8; ++tile) {
    int colstart = colblock + tile * 128;
    v4f acc[8][2];
#pragma unroll
    for (int mi = 0; mi < 8; ++mi)
#pragma unroll
      for (int fi = 0; fi < 2; ++fi) acc[mi][fi] = (v4f)0.f;

    for (int ks = 0; ks < 8; ++ks) {
      int kbase = ks * 64;
#pragma unroll
      for (int q = 0; q < 4; ++q) {
        int e = q * 256 + t;
        int ch = e >> 7, idx = e & 127;
        gload16(emb16 + ((size_t)(rowbase + idx) * 512 + kbase + ch * 8), &Rs[ch][idx][0]);
      }
#pragma unroll
      for (int q = 0; q < 4; ++q) {
        int e = q * 256 + t;
        int ch = e >> 7, idx = e & 127;
        gload16(emb16 + ((size_t)(colstart + idx) * 512 + kbase + ch * 8), &Cg[ch][idx][0]);
      }
      __syncthreads();
#pragma unroll
      for (int h = 0; h < 2; ++h) {
        v8s b[2], a[8];
#pragma unroll
        for (int fi = 0; fi < 2; ++fi)
          b[fi] = *(const v8s*)&Rs[h * 4 + l4][wv * 32 + fi * 16 + l15][0];
#pragma unroll
        for (int mi = 0; mi < 8; ++mi)
          a[mi] = *(const v8s*)&Cg[h * 4 + l4][mi * 16 + l15][0];
#pragma unroll
        for (int mi = 0; mi < 8; ++mi)
#pragma unroll
          for (int fi = 0; fi < 2; ++fi)
            acc[mi][fi] = __builtin_amdgcn_mfma_f32_16x16x32_bf16(a[mi], b[fi],
                                                                  acc[mi][fi], 0, 0, 0);
      }
      __syncthreads();
    }

    // ---- mining from accumulators ----
    int lcA[8][4];
#pragma unroll
    for (int mi = 0; mi < 8; ++mi) {
      int4 q = *(const int4*)&lab[colstart + mi * 16 + l4 * 4];
      lcA[mi][0] = q.x; lcA[mi][1] = q.y; lcA[mi][2] = q.z; lcA[mi][3] = q.w;
    }
#pragma unroll
    for (int fi = 0; fi < 2; ++fi) {
      int myrow = wv * 32 + fi * 16 + l15;
#pragma unroll
      for (int c = 0; c < 2; ++c) {
        // all-negative list
        float M[16];
#pragma unroll
        for (int j = 0; j < 16; ++j) {
          const int mi = c * 4 + (j >> 2), r = j & 3;
          float v = acc[mi][fi][r];
          M[j] = (lcA[mi][r] != rlabf[fi]) ? v : NEGV;
        }
        sort16d(M);
        xmerge16(M, 16);
        xmerge16(M, 32);
        {
          float R[16];
#pragma unroll
          for (int k = 0; k < 4; ++k) {
            float4 q4 = *(const float4*)&LrA[myrow][k * 4];
            R[k * 4] = q4.x; R[k * 4 + 1] = q4.y; R[k * 4 + 2] = q4.z; R[k * 4 + 3] = q4.w;
          }
          mergeld(R, M);
          if (l4 == 0) {
#pragma unroll
            for (int k = 0; k < 4; ++k)
              *(float4*)&LrA[myrow][k * 4] =
                  make_float4(R[k * 4], R[k * 4 + 1], R[k * 4 + 2], R[k * 4 + 3]);
          }
        }
        // semi-hard list (v < pos_min, negatives only)
        float S[16]; int add = 0;
#pragma unroll
        for (int j = 0; j < 16; ++j) {
          const int mi = c * 4 + (j >> 2), r = j & 3;
          float v = acc[mi][fi][r];
          bool sem = (lcA[mi][r] != rlabf[fi]) && (v < pmf[fi]);
          S[j] = sem ? v : NEGV;
          add += sem ? 1 : 0;
        }
        scf[fi] += add;
        sort16d(S);
        xmerge16(S, 16);
        xmerge16(S, 32);
        {
          float R[16];
#pragma unroll
          for (int k = 0; k < 4; ++k) {
            float4 q4 = *(const float4*)&LrS[myrow][k * 4];
            R[k * 4] = q4.x; R[k * 4 + 1] = q4.y; R[k * 4 + 2] = q4.z; R[k * 4 + 3] = q4.w;
          }
          mergeld(R, S);
          if (l4 == 0) {
#pragma unroll
            for (int k = 0; k < 4; ++k)
              *(float4*)&LrS[myrow][k * 4] =
                  make_float4(R[k * 4], R[k * 4 + 1], R[k * 4 + 2], R[k * 4 + 3]);
          }
        }
      }
    }
  }

  // semi-count reduce across l4 lanes, then write partials
#pragma unroll
  for (int fi = 0; fi < 2; ++fi) {
    int s = scf[fi];
    s += __shfl_xor(s, 16);
    s += __shfl_xor(s, 32);
    if (l4 == 0) scS[wv * 32 + fi * 16 + l15] = s;
  }
  __syncthreads();
  if (t < 128) {
    int grow = rowbase + t;
    size_t o = ((size_t)cb * 8192 + grow) * 16;
#pragma unroll
    for (int k = 0; k < 4; ++k) {
      *(float4*)&Lall[o + k * 4] = make_float4(LrA[t][k * 4], LrA[t][k * 4 + 1],
                                               LrA[t][k * 4 + 2], LrA[t][k * 4 + 3]);
      *(float4*)&Lsemi[o + k * 4] = make_float4(LrS[t][k * 4], LrS[t][k * 4 + 1],
                                                LrS[t][k * 4 + 2], LrS[t][k * 4 + 3]);
    }
    Scnt[cb * 8192 + grow] = scS[t];
  }
}

// merge 8 col-block partials (desc lists), masked LSE, reduce
__global__ __launch_bounds__(256) void kfin(const float* __restrict__ Lall,
                                            const float* __restrict__ Lsemi,
                                            const int* __restrict__ Scnt,
                                            const float* __restrict__ pterm,
                                            const int* __restrict__ valid,
                                            float* lsum, int* nval) {
  int i = blockIdx.x * 256 + threadIdx.x;
  float R[16], S[16], M[16];
#pragma unroll
  for (int k = 0; k < 16; ++k) {
    R[k] = Lall[(size_t)i * 16 + k];
    S[k] = Lsemi[(size_t)i * 16 + k];
  }
  int sc = Scnt[i];
  for (int c = 1; c < 8; ++c) {
    size_t o = ((size_t)c * 8192 + i) * 16;
#pragma unroll
    for (int k = 0; k < 16; ++k) M[k] = Lall[o + k];
    mergeld(R, M);
#pragma unroll
    for (int k = 0; k < 16; ++k) M[k] = Lsemi[o + k];
    mergeld(S, M);
    sc += Scnt[c * 8192 + i];
  }
  bool hs = sc > 0;
  float sel[16];
#pragma unroll
  for (int k = 0; k < 16; ++k) sel[k] = hs ? S[k] : R[k];
  float lse;
  if (sel[0] < -1e29f) {
    lse = NEGV;
  } else {
    float m = sel[0] / TEMPV;
    float se = 0.f;
#pragma unroll
    for (int k = 0; k < 16; ++k)
      if (sel[k] > -1e29f) se += expf(sel[k] / TEMPV - m);
    lse = m + logf(se);
  }
  int vd = valid[i];
  float li = vd ? (lse - pterm[i]) : 0.f;
#pragma unroll
  for (int off = 32; off; off >>= 1) {
    li += __shfl_xor(li, off);
    vd += __shfl_xor(vd, off);
  }
  __shared__ float rsd[4];
  __shared__ int rid[4];
  int wv = threadIdx.x >> 6;
  if ((threadIdx.x & 63) == 0) { rsd[wv] = li; rid[wv] = vd; }
  __syncthreads();
  if (threadIdx.x == 0) {
    atomicAdd(lsum, rsd[0] + rsd[1] + rsd[2] + rsd[3]);
    atomicAdd(nval, rid[0] + rid[1] + rid[2] + rid[3]);
  }
}

__global__ void kout(const float* lsum, const int* nval, float* out) {
  if (threadIdx.x == 0 && blockIdx.x == 0)
    out[0] = lsum[0] / (float)(nval[0] > 0 ? nval[0] : 1);
}

extern "C" void kernel_launch(void* const* d_in, const int* in_sizes, int n_in,
                              void* d_out, int out_size, void* d_ws, size_t ws_size,
                              hipStream_t stream) {
  const float* emb = (const float*)d_in[0];
  const int* lab = (const int*)d_in[1];
  float* out = (float*)d_out;

  char* wsb = (char*)d_ws;
  short* emb16 = (short*)wsb;                       // 8,388,608
  int* hist = (int*)(wsb + 8388608);                // 8,192
  int* cur = (int*)(wsb + 8396800);                 // 8,192
  int* start = (int*)(wsb + 8404992);               // 8,192
  int* rows = (int*)(wsb + 8413184);                // 32,768
  float* pmin = (float*)(wsb + 8445952);            // 32,768
  float* pterm = (float*)(wsb + 8478720);           // 32,768
  int* valid = (int*)(wsb + 8511488);               // 32,768
  float* LallW = (float*)(wsb + 8544256);           // 4,194,304
  float* LsemiW = (float*)(wsb + 12738560);         // 4,194,304
  int* ScntW = (int*)(wsb + 16932864);              // 262,144
  float* lsum = (float*)(wsb + 17195008);           // 4
  int* nval = (int*)(wsb + 17195012);               // 4

  kinit<<<8, 256, 0, stream>>>(hist, cur, lsum, nval);
  kconv<<<4096, 256, 0, stream>>>(emb, emb16);
  khist<<<32, 256, 0, stream>>>(lab, hist);
  kprefix<<<1, 256, 0, stream>>>(hist, start);
  kscatter<<<32, 256, 0, stream>>>(lab, start, cur, rows);
  kpos2<<<2048, 256, 0, stream>>>(emb16, lab, hist, start, rows, pmin, pterm, valid);
  kgemm<<<512, 256, 0, stream>>>(emb16, lab, pmin, LallW, LsemiW, ScntW);
  kfin<<<32, 256, 0, stream>>>(LallW, LsemiW, ScntW, pterm, valid, lsum, nval);
  kout<<<1, 64, 0, stream>>>(lsum, nval, out);
}

// Round 3
// 227.511 us; speedup vs baseline: 2.5241x; 1.2109x over previous
//
#include <hip/hip_runtime.h>
#include <stdint.h>
#include <stddef.h>

// HardNegativeMiningLoss on MI355X (B=8192, D=512, K=16, TEMP=0.07, labels<2048).
// kinit -> kconv(bf16) -> khist -> kprefix -> kscatter -> kpos2 -> kgemm (bf16 MFMA,
// R-panel LDS-resident, per-lane register top-16 mining) -> kfin -> kout.

#define TEMPV 0.07f
#define NEGV -1e30f

typedef short v8s __attribute__((ext_vector_type(8)));
typedef float v4f __attribute__((ext_vector_type(4)));

__device__ __forceinline__ short f2bf(float f) {
  unsigned u = __float_as_uint(f);
  unsigned r = (u + 0x7fffu + ((u >> 16) & 1u)) >> 16;  // RNE
  return (short)r;
}
__device__ __forceinline__ float bf2f(short s) {
  return __uint_as_float(((unsigned)(unsigned short)s) << 16);
}

__device__ __forceinline__ void gload16(const void* g, void* l) {
  __builtin_amdgcn_global_load_lds((const __attribute__((address_space(1))) unsigned*)g,
                                   (__attribute__((address_space(3))) unsigned*)l, 16, 0, 0);
}

// ---- Batcher odd-even mergesort network for 16 elements (63 comparators) ----
struct SNet { unsigned char a[64]; unsigned char b[64]; int n; };
constexpr SNet mknet16() {
  SNet t{}; t.n = 0;
  for (int p = 1; p < 16; p <<= 1)
    for (int k = p; k >= 1; k >>= 1)
      for (int j = k % p; j + k < 16; j += 2 * k)
        for (int i = 0; i < k; ++i) {
          int x = i + j, y = i + j + k;
          if (y < 16 && (x / (2 * p)) == (y / (2 * p))) {
            t.a[t.n] = (unsigned char)x; t.b[t.n] = (unsigned char)y; ++t.n;
          }
        }
  return t;
}
constexpr SNet NET16 = mknet16();
constexpr int NETN = NET16.n;

__device__ __forceinline__ void sort16d(float (&V)[16]) {
#pragma unroll
  for (int c = 0; c < NETN; ++c) {
    const int x = NET16.a[c], y = NET16.b[c];
    float hi = fmaxf(V[x], V[y]);
    float lo = fminf(V[x], V[y]);
    V[x] = hi; V[y] = lo;
  }
}

// clean a bitonic 16-seq into descending order
__device__ __forceinline__ void clean16d(float (&V)[16]) {
#pragma unroll
  for (int s = 8; s >= 1; s >>= 1) {
#pragma unroll
    for (int i = 0; i < 16; ++i) {
      if ((i & s) == 0) {
        float hi = fmaxf(V[i], V[i + s]);
        float lo = fminf(V[i], V[i + s]);
        V[i] = hi; V[i + s] = lo;
      }
    }
  }
}

// merge my desc-16 with xor-partner lane's desc-16 -> both get top-16 of union
__device__ __forceinline__ void xmerge16(float (&M)[16], int mask) {
  float t[16];
#pragma unroll
  for (int i = 0; i < 16; ++i) t[i] = __shfl_xor(M[15 - i], mask);
#pragma unroll
  for (int i = 0; i < 16; ++i) M[i] = fmaxf(M[i], t[i]);
  clean16d(M);
}

// R = top16(R ∪ M), both desc sorted
__device__ __forceinline__ void mergeld(float (&R)[16], const float (&M)[16]) {
  float t[16];
#pragma unroll
  for (int i = 0; i < 16; ++i) t[i] = fmaxf(M[i], R[15 - i]);
#pragma unroll
  for (int i = 0; i < 16; ++i) R[i] = t[i];
  clean16d(R);
}

// ---------------- small setup kernels ----------------
__global__ void kinit(int* hist, int* cur, float* lsum, int* nval) {
  int i = blockIdx.x * blockDim.x + threadIdx.x;
  if (i < 2048) { hist[i] = 0; cur[i] = 0; }
  if (i == 0) { *lsum = 0.f; *nval = 0; }
}

__global__ void kconv(const float* __restrict__ emb, short* __restrict__ emb16) {
  int i = (blockIdx.x * 256 + threadIdx.x) * 4;
  float4 v = *(const float4*)(emb + i);
  short4 s;
  s.x = f2bf(v.x); s.y = f2bf(v.y); s.z = f2bf(v.z); s.w = f2bf(v.w);
  *(short4*)(emb16 + i) = s;
}

__global__ void khist(const int* __restrict__ lab, int* hist) {
  int i = blockIdx.x * 256 + threadIdx.x;
  if (i < 8192) atomicAdd(&hist[lab[i]], 1);
}

__global__ __launch_bounds__(256) void kprefix(const int* __restrict__ hist,
                                               int* __restrict__ start) {
  __shared__ int part[256];
  int t = threadIdx.x;
  int v[8], loc[8], s = 0;
#pragma unroll
  for (int k = 0; k < 8; ++k) v[k] = hist[t * 8 + k];
#pragma unroll
  for (int k = 0; k < 8; ++k) { loc[k] = s; s += v[k]; }
  part[t] = s;
  __syncthreads();
  for (int off = 1; off < 256; off <<= 1) {
    int x = (t >= off) ? part[t - off] : 0;
    __syncthreads();
    part[t] += x;
    __syncthreads();
  }
  int base = (t > 0) ? part[t - 1] : 0;
#pragma unroll
  for (int k = 0; k < 8; ++k) start[t * 8 + k] = base + loc[k];
}

__global__ void kscatter(const int* __restrict__ lab, const int* __restrict__ start,
                         int* cur, int* __restrict__ rows) {
  int i = blockIdx.x * 256 + threadIdx.x;
  if (i < 8192) {
    int li = lab[i];
    int p = atomicAdd(&cur[li], 1);
    rows[start[li] + p] = i;
  }
}

__global__ __launch_bounds__(256) void kpos2(const short* __restrict__ emb16,
                                             const int* __restrict__ lab,
                                             const int* __restrict__ hist,
                                             const int* __restrict__ start,
                                             const int* __restrict__ rows,
                                             float* __restrict__ pmin,
                                             float* __restrict__ pterm,
                                             int* __restrict__ valid) {
  int t = threadIdx.x;
  int wv = t >> 6, lane = t & 63;
  int i = blockIdx.x * 4 + wv;
  int li = lab[i];
  int s0 = start[li], c = hist[li];
  float ei[8];
  v8s e = *(const v8s*)(emb16 + (size_t)i * 512 + lane * 8);
#pragma unroll
  for (int k = 0; k < 8; ++k) ei[k] = bf2f(e[k]);
  float smin = 1e30f, ssum = 0.f;
  for (int k = 0; k < c; ++k) {
    int j = rows[s0 + k];
    if (j == i) continue;
    v8s f = *(const v8s*)(emb16 + (size_t)j * 512 + lane * 8);
    float s = 0.f;
#pragma unroll
    for (int q = 0; q < 8; ++q) s += ei[q] * bf2f(f[q]);
#pragma unroll
    for (int off = 32; off; off >>= 1) s += __shfl_xor(s, off);
    smin = fminf(smin, s);
    ssum += s;
  }
  if (lane == 0) {
    int pc = c - 1, nc = 8192 - c;
    pmin[i] = smin;                                   // +1e30 when no positives
    pterm[i] = ssum / (float)(pc > 0 ? pc : 1) / TEMPV;
    valid[i] = (pc > 0 && nc > 0) ? 1 : 0;
  }
}

// ---------------- main mining GEMM ----------------
// Grid 1024 = 128 row-blocks(BM=64) x 8 col-blocks(1024 cols; cb = bid&7 -> XCD).
// R panel (64 rows x 512 K bf16 = 64KB) LDS-resident for the whole kernel; only the
// col K-tile Cg (128x64 = 16KB) is restaged per ks (hits XCD-local L2 panel).
// 4 waves, each owns 16 rows (l&15). acc[mi][r]: row = wv*16+(l&15),
// col = colstart + mi*16 + (l>>4)*4 + r -> each lane's 16 values per (c) batch all
// belong to ONE row -> per-lane register top-16 lists, merged across lanes once at end.
__global__ __launch_bounds__(256, 2) void kgemm(const short* __restrict__ emb16,
                                                const int* __restrict__ lab,
                                                const float* __restrict__ pminA,
                                                float* __restrict__ Lall,
                                                float* __restrict__ Lsemi,
                                                int* __restrict__ Scnt) {
  __shared__ short Rs[64][64][8];     // [kchunk][row][8] = 64KB, resident
  __shared__ short Cg[8][128][8];     // col K-tile, 16KB

  int t = threadIdx.x;
  int bid = blockIdx.x;
  int rb = bid >> 3, cb = bid & 7;
  int rowbase = rb * 64;
  int colblock = cb * 1024;

  int wv = t >> 6, l = t & 63;
  int l15 = l & 15, l4 = l >> 4;

  int myrow = rowbase + wv * 16 + l15;
  int rlab = lab[myrow];
  float pm = pminA[myrow];

  float RA[16], RS[16];
#pragma unroll
  for (int k = 0; k < 16; ++k) { RA[k] = NEGV; RS[k] = NEGV; }
  int scnt = 0;

  // stage the resident R panel once: 64 rows x 512 K, chunk-major [ch][row][8]
#pragma unroll
  for (int q = 0; q < 16; ++q) {
    int e = q * 256 + t;
    int ch = e >> 6, row = e & 63;
    gload16(emb16 + ((size_t)(rowbase + row) * 512 + ch * 8), &Rs[ch][row][0]);
  }

  for (int tile = 0; tile < 8; ++tile) {
    int colstart = colblock + tile * 128;
    v4f acc[8];
#pragma unroll
    for (int mi = 0; mi < 8; ++mi) acc[mi] = (v4f)0.f;

    for (int ks = 0; ks < 8; ++ks) {
      int kbase = ks * 64;
      // ensure previous MFMA reads of Cg are done before overwrite
      __syncthreads();
#pragma unroll
      for (int q = 0; q < 4; ++q) {
        int e = q * 256 + t;
        int ch = e >> 7, idx = e & 127;
        gload16(emb16 + ((size_t)(colstart + idx) * 512 + kbase + ch * 8), &Cg[ch][idx][0]);
      }
      // hide part of tile-boundary load latency under mining of previous tile:
      // (mining happens at loop bottom; here we only wait+compute)
      __syncthreads();
#pragma unroll
      for (int h = 0; h < 2; ++h) {
        v8s b = *(const v8s*)&Rs[ks * 8 + h * 4 + l4][wv * 16 + l15][0];
        v8s a[8];
#pragma unroll
        for (int mi = 0; mi < 8; ++mi)
          a[mi] = *(const v8s*)&Cg[h * 4 + l4][mi * 16 + l15][0];
#pragma unroll
        for (int mi = 0; mi < 8; ++mi)
          acc[mi] = __builtin_amdgcn_mfma_f32_16x16x32_bf16(a[mi], b, acc[mi], 0, 0, 0);
      }
    }

    // ---- per-lane register mining (no shfl, no LDS) ----
#pragma unroll
    for (int c = 0; c < 2; ++c) {
      int lc[4][4];
#pragma unroll
      for (int mm = 0; mm < 4; ++mm) {
        int4 q = *(const int4*)&lab[colstart + (c * 4 + mm) * 16 + l4 * 4];
        lc[mm][0] = q.x; lc[mm][1] = q.y; lc[mm][2] = q.z; lc[mm][3] = q.w;
      }
      float M[16];
#pragma unroll
      for (int j = 0; j < 16; ++j) {
        const int mi = c * 4 + (j >> 2), r = j & 3;
        float v = acc[mi][r];
        M[j] = (lc[j >> 2][r] != rlab) ? v : NEGV;
      }
      sort16d(M);
      mergeld(RA, M);
      // semi: mask sorted-desc M by (< pm); result is bitonic -> clean16d sorts it
      float S[16];
      int cnt = 0;
#pragma unroll
      for (int j = 0; j < 16; ++j) {
        bool keep = (M[j] > -1e29f) && (M[j] < pm);
        S[j] = keep ? M[j] : NEGV;
        cnt += keep ? 1 : 0;
      }
      scnt += cnt;
      clean16d(S);
      mergeld(RS, S);
    }
  }

  // cross-lane merge across the 4 lanes holding the same row (once per block)
  xmerge16(RA, 16); xmerge16(RA, 32);
  xmerge16(RS, 16); xmerge16(RS, 32);
  scnt += __shfl_xor(scnt, 16);
  scnt += __shfl_xor(scnt, 32);

  if (l4 == 0) {
    size_t o = ((size_t)cb * 8192 + myrow) * 16;
#pragma unroll
    for (int k = 0; k < 4; ++k) {
      *(float4*)&Lall[o + k * 4] =
          make_float4(RA[k * 4], RA[k * 4 + 1], RA[k * 4 + 2], RA[k * 4 + 3]);
      *(float4*)&Lsemi[o + k * 4] =
          make_float4(RS[k * 4], RS[k * 4 + 1], RS[k * 4 + 2], RS[k * 4 + 3]);
    }
    Scnt[cb * 8192 + myrow] = scnt;
  }
}

// merge 8 col-block partials (desc lists), masked LSE, reduce
__global__ __launch_bounds__(256) void kfin(const float* __restrict__ Lall,
                                            const float* __restrict__ Lsemi,
                                            const int* __restrict__ Scnt,
                                            const float* __restrict__ pterm,
                                            const int* __restrict__ valid,
                                            float* lsum, int* nval) {
  int i = blockIdx.x * 256 + threadIdx.x;
  float R[16], S[16], M[16];
#pragma unroll
  for (int k = 0; k < 16; ++k) {
    R[k] = Lall[(size_t)i * 16 + k];
    S[k] = Lsemi[(size_t)i * 16 + k];
  }
  int sc = Scnt[i];
  for (int c = 1; c < 8; ++c) {
    size_t o = ((size_t)c * 8192 + i) * 16;
#pragma unroll
    for (int k = 0; k < 16; ++k) M[k] = Lall[o + k];
    mergeld(R, M);
#pragma unroll
    for (int k = 0; k < 16; ++k) M[k] = Lsemi[o + k];
    mergeld(S, M);
    sc += Scnt[c * 8192 + i];
  }
  bool hs = sc > 0;
  float sel[16];
#pragma unroll
  for (int k = 0; k < 16; ++k) sel[k] = hs ? S[k] : R[k];
  float lse;
  if (sel[0] < -1e29f) {
    lse = NEGV;
  } else {
    float m = sel[0] / TEMPV;
    float se = 0.f;
#pragma unroll
    for (int k = 0; k < 16; ++k)
      if (sel[k] > -1e29f) se += expf(sel[k] / TEMPV - m);
    lse = m + logf(se);
  }
  int vd = valid[i];
  float li = vd ? (lse - pterm[i]) : 0.f;
#pragma unroll
  for (int off = 32; off; off >>= 1) {
    li += __shfl_xor(li, off);
    vd += __shfl_xor(vd, off);
  }
  __shared__ float rsd[4];
  __shared__ int rid[4];
  int wv = threadIdx.x >> 6;
  if ((threadIdx.x & 63) == 0) { rsd[wv] = li; rid[wv] = vd; }
  __syncthreads();
  if (threadIdx.x == 0) {
    atomicAdd(lsum, rsd[0] + rsd[1] + rsd[2] + rsd[3]);
    atomicAdd(nval, rid[0] + rid[1] + rid[2] + rid[3]);
  }
}

__global__ void kout(const float* lsum, const int* nval, float* out) {
  if (threadIdx.x == 0 && blockIdx.x == 0)
    out[0] = lsum[0] / (float)(nval[0] > 0 ? nval[0] : 1);
}

extern "C" void kernel_launch(void* const* d_in, const int* in_sizes, int n_in,
                              void* d_out, int out_size, void* d_ws, size_t ws_size,
                              hipStream_t stream) {
  const float* emb = (const float*)d_in[0];
  const int* lab = (const int*)d_in[1];
  float* out = (float*)d_out;

  char* wsb = (char*)d_ws;
  short* emb16 = (short*)wsb;                       // 8,388,608
  int* hist = (int*)(wsb + 8388608);                // 8,192
  int* cur = (int*)(wsb + 8396800);                 // 8,192
  int* start = (int*)(wsb + 8404992);               // 8,192
  int* rows = (int*)(wsb + 8413184);                // 32,768
  float* pmin = (float*)(wsb + 8445952);            // 32,768
  float* pterm = (float*)(wsb + 8478720);           // 32,768
  int* valid = (int*)(wsb + 8511488);               // 32,768
  float* LallW = (float*)(wsb + 8544256);           // 4,194,304
  float* LsemiW = (float*)(wsb + 12738560);         // 4,194,304
  int* ScntW = (int*)(wsb + 16932864);              // 262,144
  float* lsum = (float*)(wsb + 17195008);           // 4
  int* nval = (int*)(wsb + 17195012);               // 4

  kinit<<<8, 256, 0, stream>>>(hist, cur, lsum, nval);
  kconv<<<4096, 256, 0, stream>>>(emb, emb16);
  khist<<<32, 256, 0, stream>>>(lab, hist);
  kprefix<<<1, 256, 0, stream>>>(hist, start);
  kscatter<<<32, 256, 0, stream>>>(lab, start, cur, rows);
  kpos2<<<2048, 256, 0, stream>>>(emb16, lab, hist, start, rows, pmin, pterm, valid);
  kgemm<<<1024, 256, 0, stream>>>(emb16, lab, pmin, LallW, LsemiW, ScntW);
  kfin<<<32, 256, 0, stream>>>(LallW, LsemiW, ScntW, pterm, valid, lsum, nval);
  kout<<<1, 64, 0, stream>>>(lsum, nval, out);
}